// Round 1
// baseline (642.184 us; speedup 1.0000x reference)
//
#include <hip/hip_runtime.h>
#include <hip/hip_bf16.h>

// Window attention (Swin-style), MI355X gfx950.
// 16384 windows, 49 tokens, dim 128, 4 heads x 32. One block per window,
// 256 threads = 4 waves. Fully fused: QKV -> QK^T+bias+mask -> softmax ->
// PV -> proj, all via mfma_f32_16x16x32_bf16 with fp32 accumulation.

#define NTOK 49
#define NP   64
#define DIMC 128
#define HEADS 4
#define HD   32
#define NWM  1024
#define SCALE 0.17677669529663687f

typedef __attribute__((ext_vector_type(8))) __bf16 bf16x8;
typedef __attribute__((ext_vector_type(4))) float f32x4;

// LDS byte offsets (lifetime-aliased regions, total 57856 B -> 2 blocks/CU):
//  R1 [0..25088):    Q bf16 [4][49][64B-row]  (stage B->C1)
//                    K bf16 [4][49][64B-row] at +12544 (stage B->C1)
//                    P bf16 [4][49][128B-row] at +0     (stage C2->D)
//  R2 [25088..41472): xb bf16 [64][256B-row] (stage A->B)
//                     AO bf16 [49][256B-row] (stage D->E)
//  R3 [41472..57856): VT bf16 [4][32][128B-row] (stage B->D)
#define OFF_Q  0
#define OFF_K  12544
#define OFF_P  0
#define OFF_XB 25088
#define OFF_AO 25088
#define OFF_VT 41472
#define SMEM_BYTES 57856

__device__ __forceinline__ unsigned short f2bf(float f) {
  union { float f; unsigned u; } x; x.f = f;
  unsigned r = x.u + 0x7fffu + ((x.u >> 16) & 1u);   // round-to-nearest-even
  return (unsigned short)(r >> 16);
}

__device__ __forceinline__ f32x4 mfma16(bf16x8 a, bf16x8 b, f32x4 c) {
  return __builtin_amdgcn_mfma_f32_16x16x32_bf16(a, b, c, 0, 0, 0);
}

// ---- prep: convert weights to bf16, pre-gather rel-pos bias into padded
// [4][64][64] table with -1e30 in padded rows/cols (masks padding through
// softmax without per-element guards).
__global__ void winattn_prep(const float* __restrict__ qkv_w,
                             const float* __restrict__ proj_w,
                             const float* __restrict__ table,
                             const int* __restrict__ ridx,
                             unsigned short* __restrict__ qkv_wb,
                             unsigned short* __restrict__ proj_wb,
                             float* __restrict__ bias_g) {
  int i = blockIdx.x * 256 + threadIdx.x;
  if (i < 384 * DIMC) qkv_wb[i] = f2bf(qkv_w[i]);
  if (i < DIMC * DIMC) proj_wb[i] = f2bf(proj_w[i]);
  if (i < HEADS * 64 * 64) {
    int h = i >> 12, n = (i >> 6) & 63, m = i & 63;
    float v = -1e30f;
    if (n < NTOK && m < NTOK) v = table[ridx[n * NTOK + m] * HEADS + h];
    bias_g[i] = v;
  }
}

__launch_bounds__(256, 2)
__global__ void winattn_main(const float* __restrict__ x,
                             const float* __restrict__ mask,
                             const unsigned short* __restrict__ qkv_wb,
                             const float* __restrict__ qkv_b,
                             const unsigned short* __restrict__ proj_wb,
                             const float* __restrict__ proj_b,
                             const float* __restrict__ bias_g,
                             float* __restrict__ out) {
  __shared__ char smem[SMEM_BYTES] __attribute__((aligned(128)));
  const int tid  = threadIdx.x;
  const int w    = blockIdx.x;
  const int lane = tid & 63;
  const int wid  = tid >> 6;
  const int lr   = lane & 15;   // fragment row / output col lane index
  const int lg   = lane >> 4;   // k-group
  const f32x4 fzero = {0.f, 0.f, 0.f, 0.f};

  const float* xw = x + (size_t)w * (NTOK * DIMC);

  // ---------- Stage A: x -> LDS bf16 (rows padded to 64 with zeros) -------
  for (int i = tid; i < NTOK * 32; i += 256) {
    int n = i >> 5, c4 = i & 31;
    float4 v = *reinterpret_cast<const float4*>(xw + n * DIMC + c4 * 4);
    unsigned lo = (unsigned)f2bf(v.x) | ((unsigned)f2bf(v.y) << 16);
    unsigned hi = (unsigned)f2bf(v.z) | ((unsigned)f2bf(v.w) << 16);
    int mb = (c4 * 8) ^ ((n & 7) << 4);  // XOR-swizzle (256B-row tile)
    *reinterpret_cast<uint2*>(smem + OFF_XB + n * 256 + mb) = make_uint2(lo, hi);
  }
  for (int i = tid; i < (NP - NTOK) * 32; i += 256) {
    int n = NTOK + (i >> 5), c4 = i & 31;
    int mb = (c4 * 8) ^ ((n & 7) << 4);
    *reinterpret_cast<uint2*>(smem + OFF_XB + n * 256 + mb) = make_uint2(0u, 0u);
  }
  __syncthreads();

  // ---------- Stage B: QKV = xb @ qkv_w^T + qkv_b -------------------------
  {
    bf16x8 af[4][4];
#pragma unroll
    for (int mt = 0; mt < 4; ++mt)
#pragma unroll
      for (int kk = 0; kk < 4; ++kk) {
        int n = mt * 16 + lr;
        int mb = (kk * 64 + lg * 16) ^ ((n & 7) << 4);
        af[mt][kk] = *reinterpret_cast<const bf16x8*>(smem + OFF_XB + n * 256 + mb);
      }
    const int cb = wid * 96;  // each wave owns 96 output cols (6 N-tiles)
#pragma unroll
    for (int nt = 0; nt < 6; ++nt) {
      const int o = cb + nt * 16 + lr;  // global qkv col for this lane
      const unsigned short* wrow = qkv_wb + o * DIMC;
      bf16x8 bf[4];
#pragma unroll
      for (int kk = 0; kk < 4; ++kk)
        bf[kk] = *reinterpret_cast<const bf16x8*>(wrow + kk * 32 + lg * 8);
      f32x4 acc[4];
#pragma unroll
      for (int mt = 0; mt < 4; ++mt) acc[mt] = fzero;
#pragma unroll
      for (int kk = 0; kk < 4; ++kk)
#pragma unroll
        for (int mt = 0; mt < 4; ++mt)
          acc[mt] = mfma16(af[mt][kk], bf[kk], acc[mt]);
      const float bq = qkv_b[o];
      const int s = o >> 7;            // 0=q 1=k 2=v (uniform per tile)
      const int h = (o & 127) >> 5;    // head (uniform per tile)
      const int d = o & 31;
#pragma unroll
      for (int mt = 0; mt < 4; ++mt)
#pragma unroll
        for (int r = 0; r < 4; ++r) {
          const int n = mt * 16 + lg * 4 + r;
          const unsigned short bv = f2bf(acc[mt][r] + bq);
          if (s == 2) {
            // V transposed: VT[h][d][m=n]; padded rows (n>=49) kept (finite)
            int mb = (n * 2) ^ ((d & 7) << 4);
            *reinterpret_cast<unsigned short*>(smem + OFF_VT + (h * 32 + d) * 128 + mb) = bv;
          } else if (n < NTOK) {
            int base = (s == 0) ? OFF_Q : OFF_K;
            int mb = (d * 2) ^ ((n & 3) << 4);
            *reinterpret_cast<unsigned short*>(smem + base + (h * NTOK + n) * 64 + mb) = bv;
          }
        }
    }
  }
  __syncthreads();

  // ---------- Stage C: scores + softmax (wave == head) --------------------
  {
    const int h = wid;
    bf16x8 qf[4], kf[4];
#pragma unroll
    for (int mt = 0; mt < 4; ++mt) {
      int n = mt * 16 + lr; if (n > 48) n = 48;   // clamp padded rows
      int mb = (lg * 16) ^ ((n & 3) << 4);
      qf[mt] = *reinterpret_cast<const bf16x8*>(smem + OFF_Q + (h * NTOK + n) * 64 + mb);
    }
#pragma unroll
    for (int nt = 0; nt < 4; ++nt) {
      int m = nt * 16 + lr; if (m > 48) m = 48;
      int mb = (lg * 16) ^ ((m & 3) << 4);
      kf[nt] = *reinterpret_cast<const bf16x8*>(smem + OFF_K + (h * NTOK + m) * 64 + mb);
    }
    f32x4 sc[4][4];
#pragma unroll
    for (int mt = 0; mt < 4; ++mt)
#pragma unroll
      for (int nt = 0; nt < 4; ++nt)
        sc[mt][nt] = mfma16(qf[mt], kf[nt], fzero);

    const float* bgh = bias_g + h * 4096;
    const float* mw  = mask + (size_t)(w & (NWM - 1)) * (NTOK * NTOK);
#pragma unroll
    for (int mt = 0; mt < 4; ++mt)
#pragma unroll
      for (int r = 0; r < 4; ++r) {
        const int n  = mt * 16 + lg * 4 + r;
        const int nc = (n > 48) ? 48 : n;
#pragma unroll
        for (int nt = 0; nt < 4; ++nt) {
          const int m  = nt * 16 + lr;
          const int mc = (m > 48) ? 48 : m;
          sc[mt][nt][r] = sc[mt][nt][r] * SCALE + bgh[n * 64 + m] + mw[nc * NTOK + mc];
        }
      }
    __syncthreads();  // C1 barrier: Q/K fully consumed -> P may overwrite R1

    // in-register softmax per row: 4 in-lane + shfl_xor over 16-lane group
#pragma unroll
    for (int mt = 0; mt < 4; ++mt)
#pragma unroll
      for (int r = 0; r < 4; ++r) {
        float mx = sc[mt][0][r];
#pragma unroll
        for (int nt = 1; nt < 4; ++nt) mx = fmaxf(mx, sc[mt][nt][r]);
        mx = fmaxf(mx, __shfl_xor(mx, 1, 16));
        mx = fmaxf(mx, __shfl_xor(mx, 2, 16));
        mx = fmaxf(mx, __shfl_xor(mx, 4, 16));
        mx = fmaxf(mx, __shfl_xor(mx, 8, 16));
        float e[4]; float sum = 0.f;
#pragma unroll
        for (int nt = 0; nt < 4; ++nt) { e[nt] = __expf(sc[mt][nt][r] - mx); sum += e[nt]; }
        sum += __shfl_xor(sum, 1, 16);
        sum += __shfl_xor(sum, 2, 16);
        sum += __shfl_xor(sum, 4, 16);
        sum += __shfl_xor(sum, 8, 16);
        const float inv = __builtin_amdgcn_rcpf(sum);
        const int n = mt * 16 + lg * 4 + r;
        if (n < NTOK) {
#pragma unroll
          for (int nt = 0; nt < 4; ++nt) {
            const int m = nt * 16 + lr;
            int mb = (m * 2) ^ ((n & 7) << 4);
            *reinterpret_cast<unsigned short*>(smem + OFF_P + (h * NTOK + n) * 128 + mb) =
                f2bf(e[nt] * inv);
          }
        }
      }
  }
  // no barrier: P produced & consumed by the same wave; AO region (=xb) dead

  // ---------- Stage D: PV ------------------------------------------------
  {
    const int h = wid;
    bf16x8 pa[4][2], vb[2][2];
#pragma unroll
    for (int mt = 0; mt < 4; ++mt)
#pragma unroll
      for (int kk = 0; kk < 2; ++kk) {
        int n = mt * 16 + lr; if (n > 48) n = 48;
        int mb = (kk * 64 + lg * 16) ^ ((n & 7) << 4);
        pa[mt][kk] = *reinterpret_cast<const bf16x8*>(smem + OFF_P + (h * NTOK + n) * 128 + mb);
      }
#pragma unroll
    for (int dt = 0; dt < 2; ++dt)
#pragma unroll
      for (int kk = 0; kk < 2; ++kk) {
        const int d = dt * 16 + lr;
        int mb = (kk * 64 + lg * 16) ^ ((d & 7) << 4);
        vb[dt][kk] = *reinterpret_cast<const bf16x8*>(smem + OFF_VT + (h * 32 + d) * 128 + mb);
      }
    f32x4 oc[4][2];
#pragma unroll
    for (int mt = 0; mt < 4; ++mt)
#pragma unroll
      for (int dt = 0; dt < 2; ++dt) oc[mt][dt] = fzero;
#pragma unroll
    for (int kk = 0; kk < 2; ++kk)
#pragma unroll
      for (int mt = 0; mt < 4; ++mt)
#pragma unroll
        for (int dt = 0; dt < 2; ++dt)
          oc[mt][dt] = mfma16(pa[mt][kk], vb[dt][kk], oc[mt][dt]);
#pragma unroll
    for (int mt = 0; mt < 4; ++mt)
#pragma unroll
      for (int dt = 0; dt < 2; ++dt)
#pragma unroll
        for (int r = 0; r < 4; ++r) {
          const int n = mt * 16 + lg * 4 + r;
          if (n < NTOK) {
            const int c = h * 32 + dt * 16 + lr;
            int mb = (c * 2) ^ ((n & 7) << 4);
            *reinterpret_cast<unsigned short*>(smem + OFF_AO + n * 256 + mb) = f2bf(oc[mt][dt][r]);
          }
        }
  }
  __syncthreads();

  // ---------- Stage E: proj = AO @ proj_w^T + proj_b ----------------------
  {
    bf16x8 aof[4][4];
#pragma unroll
    for (int mt = 0; mt < 4; ++mt)
#pragma unroll
      for (int kk = 0; kk < 4; ++kk) {
        int n = mt * 16 + lr; if (n > 48) n = 48;
        int mb = (kk * 64 + lg * 16) ^ ((n & 7) << 4);
        aof[mt][kk] = *reinterpret_cast<const bf16x8*>(smem + OFF_AO + n * 256 + mb);
      }
    float* ow = out + (size_t)w * (NTOK * DIMC);
#pragma unroll
    for (int ct2 = 0; ct2 < 2; ++ct2) {
      const int c = (wid * 2 + ct2) * 16 + lr;  // each wave owns 32 cols
      const unsigned short* wrow = proj_wb + c * DIMC;
      bf16x8 wb[4];
#pragma unroll
      for (int kk = 0; kk < 4; ++kk)
        wb[kk] = *reinterpret_cast<const bf16x8*>(wrow + kk * 32 + lg * 8);
      f32x4 acc[4];
#pragma unroll
      for (int mt = 0; mt < 4; ++mt) acc[mt] = fzero;
#pragma unroll
      for (int kk = 0; kk < 4; ++kk)
#pragma unroll
        for (int mt = 0; mt < 4; ++mt)
          acc[mt] = mfma16(aof[mt][kk], wb[kk], acc[mt]);
      const float bp = proj_b[c];
#pragma unroll
      for (int mt = 0; mt < 4; ++mt)
#pragma unroll
        for (int r = 0; r < 4; ++r) {
          const int n = mt * 16 + lg * 4 + r;
          if (n < NTOK) ow[n * DIMC + c] = acc[mt][r] + bp;
        }
    }
  }
}

extern "C" void kernel_launch(void* const* d_in, const int* in_sizes, int n_in,
                              void* d_out, int out_size, void* d_ws, size_t ws_size,
                              hipStream_t stream) {
  const float* x      = (const float*)d_in[0];
  const float* mask   = (const float*)d_in[1];
  const float* qkv_w  = (const float*)d_in[2];
  const float* qkv_b  = (const float*)d_in[3];
  const float* proj_w = (const float*)d_in[4];
  const float* proj_b = (const float*)d_in[5];
  const float* table  = (const float*)d_in[6];
  const int*   ridx   = (const int*)d_in[7];

  unsigned short* qkv_wb  = (unsigned short*)d_ws;          // 384*128 bf16
  unsigned short* proj_wb = qkv_wb + 384 * DIMC;            // 128*128 bf16
  float*          bias_g  = (float*)(proj_wb + DIMC * DIMC); // [4][64][64] f32

  winattn_prep<<<192, 256, 0, stream>>>(qkv_w, proj_w, table, ridx,
                                        qkv_wb, proj_wb, bias_g);

  const int nwin = in_sizes[0] / (NTOK * DIMC);
  winattn_main<<<nwin, 256, 0, stream>>>(x, mask, qkv_wb, qkv_b, proj_wb,
                                         proj_b, bias_g, (float*)d_out);
}

// Round 4
// 549.051 us; speedup vs baseline: 1.1696x; 1.1696x over previous
//
#include <hip/hip_runtime.h>
#include <hip/hip_bf16.h>

// Window attention (Swin-style), MI355X gfx950. v4 = v1's verified compute
// structure (unswapped MFMAs, f2bf scalar epilogues, v1 swizzles, v1 barriers)
// + LDS diet only: 57856 -> 39440 B => 4 blocks/CU (was 2).
//  - XB stored as 49 rows; pad rows 49..63 are register-zeroed af[3] lanes
//  - VT rows 112B (no swizzle; non-pow2 stride banks naturally), V stores
//    guarded n<56 so all read bytes are written; 16B tail pad zeroed
//  - XB / VT / AO alias one region (barriers already order the lifetimes)

#define NTOK 49
#define DIMC 128
#define HEADS 4
#define NWM  1024
#define SCALE 0.17677669529663687f

typedef __attribute__((ext_vector_type(8))) __bf16 bf16x8;
typedef __attribute__((ext_vector_type(4))) float f32x4;

// LDS map (bytes):
//  R1 [0,25088):     Q bf16 [4][49] rows 64B @0, K @12544 (stage B->C)
//                    P bf16 [4][49] rows 128B @0 (stage C->D, aliases Q+K)
//  R2 [25088,39424): XB [49][256B] (A -> af loads)
//                    VT [4][32] rows 112B (B -> D, aliases XB after af loads)
//                    AO [49][256B] (D -> E, aliases VT after vb reads)
//  [39424,39440):    16B pad: VT row-127 kk=1/lg=3 overflow read (zeroed)
#define OFF_Q  0
#define OFF_K  12544
#define OFF_P  0
#define OFF_XB 25088
#define OFF_VT 25088
#define OFF_AO 25088
#define SMEM_BYTES 39440

__device__ __forceinline__ unsigned short f2bf(float f) {
  union { float f; unsigned u; } x; x.f = f;
  unsigned r = x.u + 0x7fffu + ((x.u >> 16) & 1u);   // round-to-nearest-even
  return (unsigned short)(r >> 16);
}

__device__ __forceinline__ f32x4 mfma16(bf16x8 a, bf16x8 b, f32x4 c) {
  return __builtin_amdgcn_mfma_f32_16x16x32_bf16(a, b, c, 0, 0, 0);
}

__device__ __forceinline__ bf16x8 zero8() {
  bf16x8 z;
#pragma unroll
  for (int j = 0; j < 8; ++j) z[j] = (__bf16)0.f;
  return z;
}

// prep: weights -> bf16; rel-pos bias pre-gathered into padded [4][64][64] f32
// with -1e30 outside the 49x49 valid square (kills padding through softmax).
__global__ void winattn_prep(const float* __restrict__ qkv_w,
                             const float* __restrict__ proj_w,
                             const float* __restrict__ table,
                             const int* __restrict__ ridx,
                             unsigned short* __restrict__ qkv_wb,
                             unsigned short* __restrict__ proj_wb,
                             float* __restrict__ bias_g) {
  int i = blockIdx.x * 256 + threadIdx.x;
  if (i < 384 * DIMC) qkv_wb[i] = f2bf(qkv_w[i]);
  if (i < DIMC * DIMC) proj_wb[i] = f2bf(proj_w[i]);
  if (i < HEADS * 64 * 64) {
    int h = i >> 12, n = (i >> 6) & 63, m = i & 63;
    float v = -1e30f;
    if (n < NTOK && m < NTOK) v = table[ridx[n * NTOK + m] * HEADS + h];
    bias_g[i] = v;
  }
}

__launch_bounds__(256, 4)
__global__ void winattn_main(const float* __restrict__ x,
                             const float* __restrict__ mask,
                             const unsigned short* __restrict__ qkv_wb,
                             const float* __restrict__ qkv_b,
                             const unsigned short* __restrict__ proj_wb,
                             const float* __restrict__ proj_b,
                             const float* __restrict__ bias_g,
                             float* __restrict__ out) {
  __shared__ char smem[SMEM_BYTES] __attribute__((aligned(128)));
  const int tid  = threadIdx.x;
  const int w    = blockIdx.x;
  const int lane = tid & 63;
  const int wid  = tid >> 6;
  const int lr   = lane & 15;
  const int lg   = lane >> 4;
  const f32x4 fzero = {0.f, 0.f, 0.f, 0.f};

  const float* xw = x + (size_t)w * (NTOK * DIMC);

  // ---------- Stage A: x -> XB bf16, 49 rows (pad handled in registers) ----
  for (int i = tid; i < NTOK * 16; i += 256) {
    int n = i >> 4, c8 = i & 15;                       // 8-float chunk
    float4 v0 = *reinterpret_cast<const float4*>(xw + n * DIMC + c8 * 8);
    float4 v1 = *reinterpret_cast<const float4*>(xw + n * DIMC + c8 * 8 + 4);
    uint4 d;
    d.x = (unsigned)f2bf(v0.x) | ((unsigned)f2bf(v0.y) << 16);
    d.y = (unsigned)f2bf(v0.z) | ((unsigned)f2bf(v0.w) << 16);
    d.z = (unsigned)f2bf(v1.x) | ((unsigned)f2bf(v1.y) << 16);
    d.w = (unsigned)f2bf(v1.z) | ((unsigned)f2bf(v1.w) << 16);
    int mb = (c8 * 16) ^ ((n & 7) << 4);               // XOR-swizzle, 256B rows
    *reinterpret_cast<uint4*>(smem + OFF_XB + n * 256 + mb) = d;
  }
  if (tid == 0)   // zero the 16B tail pad (VT row-127 overflow-read target)
    *reinterpret_cast<uint4*>(smem + SMEM_BYTES - 16) = make_uint4(0u, 0u, 0u, 0u);
  __syncthreads();

  // ---------- af fragments (X rows; rows 49..63 zeroed in-register) -------
  bf16x8 af[4][4];
#pragma unroll
  for (int mt = 0; mt < 4; ++mt)
#pragma unroll
    for (int kk = 0; kk < 4; ++kk) {
      int n = mt * 16 + lr;
      bool pad = (n > 48);
      if (pad) n = 48;
      int mb = (kk * 64 + 16 * lg) ^ ((n & 7) << 4);
      bf16x8 v = *reinterpret_cast<const bf16x8*>(smem + OFF_XB + n * 256 + mb);
      af[mt][kk] = pad ? zero8() : v;
    }
  __syncthreads();   // XB dead; VT writes (aliasing XB) may proceed

  // ---------- Stage B: QKV = xb @ qkv_w^T + qkv_b (v1 mapping) ------------
  {
    const int cb = wid * 96;  // each wave owns 96 output cols (6 N-tiles)
#pragma unroll
    for (int nt = 0; nt < 6; ++nt) {
      const int o = cb + nt * 16 + lr;  // global qkv col for this lane
      const unsigned short* wrow = qkv_wb + o * DIMC;
      bf16x8 bf[4];
#pragma unroll
      for (int kk = 0; kk < 4; ++kk)
        bf[kk] = *reinterpret_cast<const bf16x8*>(wrow + kk * 32 + lg * 8);
      f32x4 acc[4];
#pragma unroll
      for (int mt = 0; mt < 4; ++mt) acc[mt] = fzero;
#pragma unroll
      for (int kk = 0; kk < 4; ++kk)
#pragma unroll
        for (int mt = 0; mt < 4; ++mt)
          acc[mt] = mfma16(af[mt][kk], bf[kk], acc[mt]);
      const float bq = qkv_b[o];
      const int s  = o >> 7;            // 0=q 1=k 2=v (uniform per tile)
      const int h2 = (o & 127) >> 5;    // head (uniform per tile)
      const int d  = o & 31;
#pragma unroll
      for (int mt = 0; mt < 4; ++mt)
#pragma unroll
        for (int r = 0; r < 4; ++r) {
          const int n = mt * 16 + lg * 4 + r;
          const unsigned short bv = f2bf(acc[mt][r] + bq);
          if (s == 2) {
            if (n < 56)   // VT[h2][d][n], 112B rows, unswizzled
              *reinterpret_cast<unsigned short*>(
                  smem + OFF_VT + (h2 * 32 + d) * 112 + n * 2) = bv;
          } else if (n < NTOK) {
            int base = (s == 0) ? OFF_Q : OFF_K;
            int mb = (d * 2) ^ ((n & 3) << 4);
            *reinterpret_cast<unsigned short*>(
                smem + base + (h2 * NTOK + n) * 64 + mb) = bv;
          }
        }
    }
  }
  __syncthreads();   // Q/K/VT written cross-wave -> barrier before stage C

  // ---------- Stage C: scores + softmax (wave == head, v1 verbatim) -------
  const int h = wid;
  {
    bf16x8 qf[4], kf[4];
#pragma unroll
    for (int mt = 0; mt < 4; ++mt) {
      int n = mt * 16 + lr; if (n > 48) n = 48;   // clamp padded rows
      int mb = (lg * 16) ^ ((n & 3) << 4);
      qf[mt] = *reinterpret_cast<const bf16x8*>(smem + OFF_Q + (h * NTOK + n) * 64 + mb);
    }
#pragma unroll
    for (int nt = 0; nt < 4; ++nt) {
      int m = nt * 16 + lr; if (m > 48) m = 48;
      int mb = (lg * 16) ^ ((m & 3) << 4);
      kf[nt] = *reinterpret_cast<const bf16x8*>(smem + OFF_K + (h * NTOK + m) * 64 + mb);
    }
    f32x4 sc[4][4];
#pragma unroll
    for (int mt = 0; mt < 4; ++mt)
#pragma unroll
      for (int nt = 0; nt < 4; ++nt)
        sc[mt][nt] = mfma16(qf[mt], kf[nt], fzero);

    const float* bgh = bias_g + h * 4096;
    const float* mw  = mask + (size_t)(w & (NWM - 1)) * (NTOK * NTOK);
#pragma unroll
    for (int mt = 0; mt < 4; ++mt)
#pragma unroll
      for (int r = 0; r < 4; ++r) {
        const int n  = mt * 16 + lg * 4 + r;
        const int nc = (n > 48) ? 48 : n;
#pragma unroll
        for (int nt = 0; nt < 4; ++nt) {
          const int m  = nt * 16 + lr;
          const int mc = (m > 48) ? 48 : m;
          sc[mt][nt][r] = sc[mt][nt][r] * SCALE + bgh[n * 64 + m] + mw[nc * NTOK + mc];
        }
      }
    __syncthreads();  // all Q/K reads done -> P may overwrite R1

    // softmax per row n: 4 in-lane (nt) + shfl_xor over the 16-lane group
#pragma unroll
    for (int mt = 0; mt < 4; ++mt)
#pragma unroll
      for (int r = 0; r < 4; ++r) {
        float mx = sc[mt][0][r];
#pragma unroll
        for (int nt = 1; nt < 4; ++nt) mx = fmaxf(mx, sc[mt][nt][r]);
        mx = fmaxf(mx, __shfl_xor(mx, 1, 16));
        mx = fmaxf(mx, __shfl_xor(mx, 2, 16));
        mx = fmaxf(mx, __shfl_xor(mx, 4, 16));
        mx = fmaxf(mx, __shfl_xor(mx, 8, 16));
        float e[4]; float sum = 0.f;
#pragma unroll
        for (int nt = 0; nt < 4; ++nt) { e[nt] = __expf(sc[mt][nt][r] - mx); sum += e[nt]; }
        sum += __shfl_xor(sum, 1, 16);
        sum += __shfl_xor(sum, 2, 16);
        sum += __shfl_xor(sum, 4, 16);
        sum += __shfl_xor(sum, 8, 16);
        const float inv = __builtin_amdgcn_rcpf(sum);
        const int n = mt * 16 + lg * 4 + r;
        if (n < NTOK) {
#pragma unroll
          for (int nt = 0; nt < 4; ++nt) {
            const int m = nt * 16 + lr;
            int mb = (m * 2) ^ ((n & 7) << 4);
            *reinterpret_cast<unsigned short*>(smem + OFF_P + (h * NTOK + n) * 128 + mb) =
                f2bf(e[nt] * inv);
          }
        }
      }
  }
  // P wave-private -> no barrier

  // ---------- Stage D: PV (v1 verbatim; VT rows 112B unswizzled) ----------
  {
    bf16x8 pa[4][2], vb[2][2];
#pragma unroll
    for (int mt = 0; mt < 4; ++mt)
#pragma unroll
      for (int kk = 0; kk < 2; ++kk) {
        int n = mt * 16 + lr; if (n > 48) n = 48;
        int mb = (kk * 64 + lg * 16) ^ ((n & 7) << 4);
        pa[mt][kk] = *reinterpret_cast<const bf16x8*>(smem + OFF_P + (h * NTOK + n) * 128 + mb);
      }
#pragma unroll
    for (int dt = 0; dt < 2; ++dt)
#pragma unroll
      for (int kk = 0; kk < 2; ++kk) {
        const int d = dt * 16 + lr;
        vb[dt][kk] = *reinterpret_cast<const bf16x8*>(
            smem + OFF_VT + (h * 32 + d) * 112 + kk * 64 + 16 * lg);
      }
    f32x4 oc[4][2];
#pragma unroll
    for (int mt = 0; mt < 4; ++mt)
#pragma unroll
      for (int dt = 0; dt < 2; ++dt) oc[mt][dt] = fzero;
#pragma unroll
    for (int kk = 0; kk < 2; ++kk)
#pragma unroll
      for (int mt = 0; mt < 4; ++mt)
#pragma unroll
        for (int dt = 0; dt < 2; ++dt)
          oc[mt][dt] = mfma16(pa[mt][kk], vb[dt][kk], oc[mt][dt]);
    __syncthreads();   // all VT reads done -> AO may overwrite VT
#pragma unroll
    for (int mt = 0; mt < 4; ++mt)
#pragma unroll
      for (int dt = 0; dt < 2; ++dt)
#pragma unroll
        for (int r = 0; r < 4; ++r) {
          const int n = mt * 16 + lg * 4 + r;
          if (n < NTOK) {
            const int c = h * 32 + dt * 16 + lr;
            int mb = (c * 2) ^ ((n & 7) << 4);
            *reinterpret_cast<unsigned short*>(smem + OFF_AO + n * 256 + mb) =
                f2bf(oc[mt][dt][r]);
          }
        }
  }
  __syncthreads();

  // ---------- Stage E: proj = AO @ proj_w^T + proj_b (v1 verbatim) --------
  {
    bf16x8 aof[4][4];
#pragma unroll
    for (int mt = 0; mt < 4; ++mt)
#pragma unroll
      for (int kk = 0; kk < 4; ++kk) {
        int n = mt * 16 + lr; if (n > 48) n = 48;      // keep in AO bounds
        int s16 = 4 * kk + lg;
        aof[mt][kk] = *reinterpret_cast<const bf16x8*>(
            smem + OFF_AO + n * 256 + (((s16 & 8) | ((s16 ^ (n & 7)) & 7)) << 4));
      }
    float* ow = out + (size_t)w * (NTOK * DIMC);
#pragma unroll
    for (int ct = 0; ct < 2; ++ct) {
      const int c = (wid * 2 + ct) * 16 + lr;  // each wave owns 32 cols
      const unsigned short* wrow = proj_wb + c * DIMC;
      bf16x8 wb[4];
#pragma unroll
      for (int kk = 0; kk < 4; ++kk)
        wb[kk] = *reinterpret_cast<const bf16x8*>(wrow + kk * 32 + lg * 8);
      f32x4 acc[4];
#pragma unroll
      for (int mt = 0; mt < 4; ++mt) acc[mt] = fzero;
#pragma unroll
      for (int kk = 0; kk < 4; ++kk)
#pragma unroll
        for (int mt = 0; mt < 4; ++mt)
          acc[mt] = mfma16(aof[mt][kk], wb[kk], acc[mt]);
      const float bp = proj_b[c];
#pragma unroll
      for (int mt = 0; mt < 4; ++mt)
#pragma unroll
        for (int r = 0; r < 4; ++r) {
          const int n = mt * 16 + lg * 4 + r;
          if (n < NTOK) ow[n * DIMC + c] = acc[mt][r] + bp;
        }
    }
  }
}

extern "C" void kernel_launch(void* const* d_in, const int* in_sizes, int n_in,
                              void* d_out, int out_size, void* d_ws, size_t ws_size,
                              hipStream_t stream) {
  const float* x      = (const float*)d_in[0];
  const float* mask   = (const float*)d_in[1];
  const float* qkv_w  = (const float*)d_in[2];
  const float* qkv_b  = (const float*)d_in[3];
  const float* proj_w = (const float*)d_in[4];
  const float* proj_b = (const float*)d_in[5];
  const float* table  = (const float*)d_in[6];
  const int*   ridx   = (const int*)d_in[7];

  unsigned short* qkv_wb  = (unsigned short*)d_ws;           // 384*128 bf16
  unsigned short* proj_wb = qkv_wb + 384 * DIMC;             // 128*128 bf16
  float*          bias_g  = (float*)(proj_wb + DIMC * DIMC); // [4][64][64] f32

  winattn_prep<<<192, 256, 0, stream>>>(qkv_w, proj_w, table, ridx,
                                        qkv_wb, proj_wb, bias_g);

  const int nwin = in_sizes[0] / (NTOK * DIMC);
  winattn_main<<<nwin, 256, 0, stream>>>(x, mask, qkv_wb, qkv_b, proj_wb,
                                         proj_b, bias_g, (float*)d_out);
}